// Round 6
// baseline (1246.843 us; speedup 1.0000x reference)
//
#include <hip/hip_runtime.h>
#include <math.h>

// APPNP: h = relu(x@W1+b1)@W2+b2 ; z_{k+1} = 0.9*Ahat z_k + 0.1*h (10 steps); log_softmax
// Ahat = D^-1/2 (A + I) D^-1/2.
// u-space propagation: u = D^-1/2 z -> (Ahat z)_i = dinv_i * (sum_{j in N(i)} u_j + u_i).
// CSR via bucketed counting sort. u, ah=0.1*h stored bf16; accumulation f32.
// Prop v2: 4 edges per wave-gather (ushort4/lane), predicated tail to zero-row u[N].

constexpr int KSTEPS = 10;

typedef __attribute__((ext_vector_type(8))) short short8;
typedef __attribute__((ext_vector_type(4))) float f32x4;

static __device__ __forceinline__ unsigned short f2bf(float f) {
    unsigned u = __builtin_bit_cast(unsigned, f);
    unsigned r = (u + 0x7FFFu + ((u >> 16) & 1u)) >> 16;
    return (unsigned short)r;
}
static __device__ __forceinline__ float bf2f(unsigned short b) {
    unsigned u = (unsigned)b << 16;
    return __builtin_bit_cast(float, u);
}
static __device__ __forceinline__ float lo16(unsigned d) {
    return __builtin_bit_cast(float, d << 16);
}
static __device__ __forceinline__ float hi16(unsigned d) {
    return __builtin_bit_cast(float, d & 0xFFFF0000u);
}

// ---------------- bucketed CSR build ----------------
// bucket = row >> 8 (256 rows per bucket); NB = ceil(N/256) buckets

__global__ void k_zero(int* __restrict__ p, int n) {
    int i = blockIdx.x * 256 + threadIdx.x;
    if (i < n) p[i] = 0;
}

__global__ void k_hist(const int* __restrict__ ei, int* __restrict__ btot, int E, int NB) {
    __shared__ int hist[512];
    for (int t = threadIdx.x; t < NB; t += 256) hist[t] = 0;
    __syncthreads();
    int base = blockIdx.x * 4096;
#pragma unroll
    for (int k = 0; k < 16; ++k) {
        int e = base + k * 256 + threadIdx.x;
        if (e < E) atomicAdd(&hist[ei[e] >> 8], 1);
    }
    __syncthreads();
    for (int t = threadIdx.x; t < NB; t += 256) {
        int c = hist[t];
        if (c) atomicAdd(&btot[t], c);
    }
}

__global__ void k_scanb(const int* __restrict__ btot, int* __restrict__ bstart,
                        int* __restrict__ bcur, int* __restrict__ row_ptr,
                        int NB, int N, int E) {
    __shared__ int lds[512];
    int t = threadIdx.x;
    int v0 = (t < NB) ? btot[t] : 0;
    int v = v0;
    lds[t] = v;
    __syncthreads();
    for (int o = 1; o < 512; o <<= 1) {
        int a = (t >= o) ? lds[t - o] : 0;
        __syncthreads();
        v += a;
        lds[t] = v;
        __syncthreads();
    }
    if (t < NB) {
        int ex = v - v0;
        bstart[t] = ex;
        bcur[t] = ex;
    }
    if (t == 0) {
        bstart[NB] = E;
        row_ptr[N] = E;
    }
}

__launch_bounds__(256)
__global__ void k_part(const int* __restrict__ ei, int* __restrict__ bcur,
                       int2* __restrict__ ebuf, int E, int NB) {
    __shared__ int hist[512], rebase[512], lcur[512];
    for (int t = threadIdx.x; t < NB; t += 256) { hist[t] = 0; lcur[t] = 0; }
    __syncthreads();
    int base = blockIdx.x * 4096;
    int r[16], c[16];
#pragma unroll
    for (int k = 0; k < 16; ++k) {
        int e = base + k * 256 + threadIdx.x;
        bool ok = e < E;
        r[k] = ok ? ei[e] : -1;
        c[k] = ok ? ei[E + e] : 0;
        if (ok) atomicAdd(&hist[r[k] >> 8], 1);
    }
    __syncthreads();
    for (int t = threadIdx.x; t < NB; t += 256) {
        int cnt = hist[t];
        rebase[t] = cnt ? atomicAdd(&bcur[t], cnt) : 0;
    }
    __syncthreads();
#pragma unroll
    for (int k = 0; k < 16; ++k) {
        if (r[k] >= 0) {
            int b = r[k] >> 8;
            int pos = rebase[b] + atomicAdd(&lcur[b], 1);
            ebuf[pos] = make_int2(r[k], c[k]);
        }
    }
}

__launch_bounds__(256)
__global__ void k_bucket(const int2* __restrict__ ebuf, const int* __restrict__ bstart,
                         int* __restrict__ row_ptr, float* __restrict__ dinv,
                         int* __restrict__ cols, int N) {
    __shared__ int cnt[256], cur[256], lds[256];
    int b = blockIdx.x, t = threadIdx.x;
    int s = bstart[b], e2 = bstart[b + 1];
    cnt[t] = 0;
    __syncthreads();
    for (int i = s + t; i < e2; i += 256) {
        int2 p = ebuf[i];
        atomicAdd(&cnt[p.x & 255], 1);
    }
    __syncthreads();
    int v0 = cnt[t];
    int v = v0;
    lds[t] = v;
    __syncthreads();
    for (int o = 1; o < 256; o <<= 1) {
        int a = (t >= o) ? lds[t - o] : 0;
        __syncthreads();
        v += a;
        lds[t] = v;
        __syncthreads();
    }
    int excl = v - v0;
    int row = (b << 8) + t;
    if (row < N) {
        row_ptr[row] = s + excl;
        dinv[row] = rsqrtf((float)(v0 + 1));
    }
    cur[t] = s + excl;
    __syncthreads();
    for (int i = s + t; i < e2; i += 256) {
        int2 p = ebuf[i];
        int pos = atomicAdd(&cur[p.x & 255], 1);
        cols[pos] = p.y;
    }
}

// zero-pad row N of the three u buffers (predicated tail gathers land here)
__global__ void k_zrow(unsigned short* __restrict__ a, unsigned short* __restrict__ b,
                       unsigned short* __restrict__ c, int N) {
    int t = threadIdx.x;  // 64
    size_t o = (size_t)N * 64 + t;
    a[o] = 0; b[o] = 0; c[o] = 0;
}

// ---------------- weight packing into MFMA fragment order ----------------
__global__ void k_pack_w1(const float* __restrict__ w1, short* __restrict__ w1f) {
    int t = blockIdx.x * 256 + threadIdx.x;  // 65536 total
    int j = t & 7, lane = (t >> 3) & 63, nb = (t >> 9) & 3, kb = t >> 11;
    int k = kb * 32 + ((lane >> 4) << 3) + j;
    int c = nb * 16 + (lane & 15);
    w1f[t] = f2bf(w1[k * 64 + c]);
}

__global__ void k_pack_w2(const float* __restrict__ w2, short* __restrict__ w2f) {
    int t = blockIdx.x * 256 + threadIdx.x;  // 4096 total
    int j = t & 7, lane = (t >> 3) & 63, nb = (t >> 9) & 3, kb = (t >> 11) & 1;
    int k = kb * 32 + ((lane >> 4) << 3) + j;
    int c = nb * 16 + (lane & 15);
    w2f[t] = f2bf(w2[k * 64 + c]);
}

// ---------------- fused 2-layer MLP via MFMA ----------------
__launch_bounds__(256)
__global__ void k_mlp(const float* __restrict__ x, const short8* __restrict__ w1f,
                      const float* __restrict__ b1, const short8* __restrict__ w2f,
                      const float* __restrict__ b2, const float* __restrict__ dinv,
                      unsigned short* __restrict__ ah, unsigned short* __restrict__ u0,
                      int M, int F) {
    __shared__ __align__(16) short c1s[4][16][64];
    int tid = threadIdx.x;
    int w = tid >> 6, lane = tid & 63;
    int hi = lane >> 4, lx = lane & 15;
    int rbase = blockIdx.x * 64 + w * 16;
    int row = rbase + lx;
    size_t rowc = (row < M) ? (size_t)row : (size_t)(M - 1);
    const float* xr = x + rowc * (size_t)F + hi * 8;

    f32x4 acc[4];
#pragma unroll
    for (int nb = 0; nb < 4; ++nb) acc[nb] = (f32x4){0.f, 0.f, 0.f, 0.f};

    int KK = F >> 5;
#pragma unroll 2
    for (int kk = 0; kk < KK; ++kk) {
        float4 a0 = *reinterpret_cast<const float4*>(xr + kk * 32);
        float4 a1 = *reinterpret_cast<const float4*>(xr + kk * 32 + 4);
        short8 af;
        af[0] = f2bf(a0.x); af[1] = f2bf(a0.y); af[2] = f2bf(a0.z); af[3] = f2bf(a0.w);
        af[4] = f2bf(a1.x); af[5] = f2bf(a1.y); af[6] = f2bf(a1.z); af[7] = f2bf(a1.w);
#pragma unroll
        for (int nb = 0; nb < 4; ++nb) {
            short8 bf = w1f[(kk * 4 + nb) * 64 + lane];
            acc[nb] = __builtin_amdgcn_mfma_f32_16x16x32_bf16(af, bf, acc[nb], 0, 0, 0);
        }
    }

    short* my = &c1s[w][0][0];
#pragma unroll
    for (int nb = 0; nb < 4; ++nb) {
        int col = nb * 16 + lx;
        float bb = b1[col];
#pragma unroll
        for (int r = 0; r < 4; ++r) {
            int rr = hi * 4 + r;
            my[rr * 64 + col] = (short)f2bf(fmaxf(acc[nb][r] + bb, 0.f));
        }
    }
    __syncthreads();

    f32x4 acc2[4];
#pragma unroll
    for (int nb = 0; nb < 4; ++nb) acc2[nb] = (f32x4){0.f, 0.f, 0.f, 0.f};
#pragma unroll
    for (int kb = 0; kb < 2; ++kb) {
        short8 af2 = *reinterpret_cast<const short8*>(&my[lx * 64 + kb * 32 + hi * 8]);
#pragma unroll
        for (int nb = 0; nb < 4; ++nb) {
            short8 bf2 = w2f[(kb * 4 + nb) * 64 + lane];
            acc2[nb] = __builtin_amdgcn_mfma_f32_16x16x32_bf16(af2, bf2, acc2[nb], 0, 0, 0);
        }
    }

#pragma unroll
    for (int r = 0; r < 4; ++r) {
        int orow = rbase + hi * 4 + r;
        float dv = (orow < M) ? dinv[orow] : 0.f;
#pragma unroll
        for (int nb = 0; nb < 4; ++nb) {
            int col = nb * 16 + lx;
            if (orow < M) {
                float v = acc2[nb][r] + b2[col];
                ah[(size_t)orow * 64 + col] = f2bf(0.1f * v);
                u0[(size_t)orow * 64 + col] = f2bf(dv * v);
            }
        }
    }
}

// ---------------- propagation v2: 4 edges per wave-gather ----------------
// lane = 16*g + fl: group g in [0,4) handles edge e+g; fl owns features fl*4..fl*4+3.
__global__ void k_prop(const unsigned short* __restrict__ uin, const unsigned short* __restrict__ ah,
                       const float* __restrict__ dinv, const int* __restrict__ row_ptr,
                       const int* __restrict__ cols, unsigned short* __restrict__ uout, int n) {
    int wid = threadIdx.x >> 6;
    int lane = threadIdx.x & 63;
    int i = blockIdx.x * 4 + wid;
    if (i >= n) return;
    int g = lane >> 4;
    int fl = lane & 15;
    float di = dinv[i];
    size_t i64 = (size_t)i * 64;
    size_t fo = (size_t)(fl * 4);
    int e0 = row_ptr[i], end = row_ptr[i + 1];
    float a0 = 0.f, a1 = 0.f, a2 = 0.f, a3 = 0.f;
    for (int eb = e0; eb < end; eb += 4) {
        int ep = eb + g;
        if (ep < end) {
            int c = cols[ep];
            uint2 d = *reinterpret_cast<const uint2*>(uin + (size_t)c * 64 + fo);
            a0 += lo16(d.x); a1 += hi16(d.x);
            a2 += lo16(d.y); a3 += hi16(d.y);
        }
    }
    // reduce across the 4 edge-groups (lanes l, l^16, l^32, l^48)
#pragma unroll
    for (int o = 16; o <= 32; o <<= 1) {
        a0 += __shfl_xor(a0, o, 64);
        a1 += __shfl_xor(a1, o, 64);
        a2 += __shfl_xor(a2, o, 64);
        a3 += __shfl_xor(a3, o, 64);
    }
    uint2 sd = *reinterpret_cast<const uint2*>(uin + i64 + fo);
    uint2 ad = *reinterpret_cast<const uint2*>(ah + i64 + fo);
    float w = 0.9f * di;
    float z0 = fmaf(w, a0 + lo16(sd.x), lo16(ad.x));
    float z1 = fmaf(w, a1 + hi16(sd.x), hi16(ad.x));
    float z2 = fmaf(w, a2 + lo16(sd.y), lo16(ad.y));
    float z3 = fmaf(w, a3 + hi16(sd.y), hi16(ad.y));
    if (g == 0) {
        uint2 o2;
        o2.x = (unsigned)f2bf(di * z0) | ((unsigned)f2bf(di * z1) << 16);
        o2.y = (unsigned)f2bf(di * z2) | ((unsigned)f2bf(di * z3) << 16);
        *reinterpret_cast<uint2*>(uout + i64 + fo) = o2;
    }
}

// final step fused with log_softmax, writes f32 out
__global__ void k_prop_lsm(const unsigned short* __restrict__ uin, const unsigned short* __restrict__ ah,
                           const float* __restrict__ dinv, const int* __restrict__ row_ptr,
                           const int* __restrict__ cols, float* __restrict__ out, int n) {
    int wid = threadIdx.x >> 6;
    int lane = threadIdx.x & 63;
    int i = blockIdx.x * 4 + wid;
    if (i >= n) return;
    int g = lane >> 4;
    int fl = lane & 15;
    float di = dinv[i];
    size_t i64 = (size_t)i * 64;
    size_t fo = (size_t)(fl * 4);
    int e0 = row_ptr[i], end = row_ptr[i + 1];
    float a0 = 0.f, a1 = 0.f, a2 = 0.f, a3 = 0.f;
    for (int eb = e0; eb < end; eb += 4) {
        int ep = eb + g;
        if (ep < end) {
            int c = cols[ep];
            uint2 d = *reinterpret_cast<const uint2*>(uin + (size_t)c * 64 + fo);
            a0 += lo16(d.x); a1 += hi16(d.x);
            a2 += lo16(d.y); a3 += hi16(d.y);
        }
    }
#pragma unroll
    for (int o = 16; o <= 32; o <<= 1) {
        a0 += __shfl_xor(a0, o, 64);
        a1 += __shfl_xor(a1, o, 64);
        a2 += __shfl_xor(a2, o, 64);
        a3 += __shfl_xor(a3, o, 64);
    }
    uint2 sd = *reinterpret_cast<const uint2*>(uin + i64 + fo);
    uint2 ad = *reinterpret_cast<const uint2*>(ah + i64 + fo);
    float w = 0.9f * di;
    float z0 = fmaf(w, a0 + lo16(sd.x), lo16(ad.x));
    float z1 = fmaf(w, a1 + hi16(sd.x), hi16(ad.x));
    float z2 = fmaf(w, a2 + lo16(sd.y), lo16(ad.y));
    float z3 = fmaf(w, a3 + hi16(sd.y), hi16(ad.y));
    // softmax over 64 features: local max/sum over 4, then xor-reduce across 16 feature-lanes
    float m = fmaxf(fmaxf(z0, z1), fmaxf(z2, z3));
#pragma unroll
    for (int o = 1; o <= 8; o <<= 1) m = fmaxf(m, __shfl_xor(m, o, 64));
    float s = expf(z0 - m) + expf(z1 - m) + expf(z2 - m) + expf(z3 - m);
#pragma unroll
    for (int o = 1; o <= 8; o <<= 1) s += __shfl_xor(s, o, 64);
    float ls = m + logf(s);
    if (g == 0) {
        float4 o4 = make_float4(z0 - ls, z1 - ls, z2 - ls, z3 - ls);
        *reinterpret_cast<float4*>(out + i64 + fo) = o4;
    }
}

// ---------------- launch ----------------
extern "C" void kernel_launch(void* const* d_in, const int* in_sizes, int n_in,
                              void* d_out, int out_size, void* d_ws, size_t ws_size,
                              hipStream_t stream) {
    const float* x  = (const float*)d_in[0];
    const float* w1 = (const float*)d_in[1];
    const float* b1 = (const float*)d_in[2];
    const float* w2 = (const float*)d_in[3];
    const float* b2 = (const float*)d_in[4];
    const int*   ei = (const int*)d_in[5];
    // d_in[6] = K (always 10; launch count must be graph-static)

    int F = in_sizes[1] / 64;         // 1024
    int N = in_sizes[0] / F;          // 100000
    int E = in_sizes[5] / 2;          // 3200000
    int NB = (N + 255) >> 8;          // 391 buckets

    char* p = (char*)d_ws;
    auto alloc = [&](size_t bytes) {
        void* r = (void*)p;
        p += (bytes + 255) & ~(size_t)255;
        return r;
    };
    unsigned short* ah   = (unsigned short*)alloc((size_t)N * 64 * 2);
    unsigned short* u0   = (unsigned short*)alloc((size_t)(N + 1) * 64 * 2);
    unsigned short* uA   = (unsigned short*)alloc((size_t)(N + 1) * 64 * 2);
    unsigned short* uB   = (unsigned short*)alloc((size_t)(N + 1) * 64 * 2);
    float* dinv    = (float*)alloc((size_t)N * 4);
    int*   row_ptr = (int*)alloc((size_t)(N + 1) * 4);
    int*   btot    = (int*)alloc(2048);
    int*   bstart  = (int*)alloc(2048);
    int*   bcur    = (int*)alloc(2048);
    int2*  ebuf    = (int2*)alloc((size_t)E * 8);
    int*   cols    = (int*)alloc((size_t)(E + 64) * 4);
    short* w1f     = (short*)alloc((size_t)F * 64 * 2);
    short* w2f     = (short*)alloc((size_t)64 * 64 * 2);

    int neb = (E + 4095) / 4096;

    k_zero<<<2, 256, 0, stream>>>(btot, NB);
    k_hist<<<neb, 256, 0, stream>>>(ei, btot, E, NB);
    k_scanb<<<1, 512, 0, stream>>>(btot, bstart, bcur, row_ptr, NB, N, E);
    k_part<<<neb, 256, 0, stream>>>(ei, bcur, ebuf, E, NB);
    k_bucket<<<NB, 256, 0, stream>>>(ebuf, bstart, row_ptr, dinv, cols, N);
    k_zrow<<<1, 64, 0, stream>>>(u0, uA, uB, N);
    k_pack_w1<<<(F * 64) / 256, 256, 0, stream>>>(w1, w1f);
    k_pack_w2<<<16, 256, 0, stream>>>(w2, w2f);
    k_mlp<<<(N + 63) / 64, 256, 0, stream>>>(x, (const short8*)w1f, b1,
                                             (const short8*)w2f, b2, dinv, ah, u0, N, F);

    const unsigned short* uin = u0;
    unsigned short* bufs[2] = {uA, uB};
    for (int k = 0; k < KSTEPS - 1; ++k) {
        unsigned short* uo = bufs[k & 1];
        k_prop<<<(N + 3) / 4, 256, 0, stream>>>(uin, ah, dinv, row_ptr, cols, uo, N);
        uin = uo;
    }
    k_prop_lsm<<<(N + 3) / 4, 256, 0, stream>>>(uin, ah, dinv, row_ptr, cols, (float*)d_out, N);
}

// Round 7
// 1099.231 us; speedup vs baseline: 1.1343x; 1.1343x over previous
//
#include <hip/hip_runtime.h>
#include <math.h>

// APPNP: h = relu(x@W1+b1)@W2+b2 ; z_{k+1} = 0.9*Ahat z_k + 0.1*h (10 steps); log_softmax
// Ahat = D^-1/2 (A + I) D^-1/2.
// u-space propagation: u = D^-1/2 z -> (Ahat z)_i = dinv_i * (sum_{j in N(i)} u_j + u_i).
// CSR via bucketed counting sort (ebuf packed 4B). MLP via split-bf16 3-term MFMA
// (error ~2^-16). Propagation state u in fp8 e4m3 (64B/row gathers); ah=0.1*h bf16;
// accumulation f32.

constexpr int KSTEPS = 10;

typedef __attribute__((ext_vector_type(8))) short short8;
typedef __attribute__((ext_vector_type(4))) float f32x4;

static __device__ __forceinline__ unsigned short f2bf(float f) {
    unsigned u = __builtin_bit_cast(unsigned, f);
    unsigned r = (u + 0x7FFFu + ((u >> 16) & 1u)) >> 16;
    return (unsigned short)r;
}
static __device__ __forceinline__ float bf2f(unsigned short b) {
    unsigned u = (unsigned)b << 16;
    return __builtin_bit_cast(float, u);
}
// split f32 -> (hi = truncated bf16, lo = RNE bf16 of remainder); hi+lo error ~2^-17
static __device__ __forceinline__ void splitbf(float f, short* hi, short* lo) {
    unsigned u = __builtin_bit_cast(unsigned, f);
    *hi = (short)(u >> 16);
    float rem = f - __builtin_bit_cast(float, u & 0xFFFF0000u);
    *lo = (short)f2bf(rem);
}
static __device__ __forceinline__ unsigned char f2fp8(float f) {
    int p = __builtin_amdgcn_cvt_pk_fp8_f32(f, f, 0, false);
    return (unsigned char)(p & 0xFF);
}
static __device__ __forceinline__ float fp82f(unsigned b) {
    return __builtin_amdgcn_cvt_f32_fp8((int)b, 0);
}

// ---------------- bucketed CSR build ----------------
// bucket = row >> 8 (256 rows per bucket); NB = ceil(N/256) buckets

__global__ void k_zero(int* __restrict__ p, int n) {
    int i = blockIdx.x * 256 + threadIdx.x;
    if (i < n) p[i] = 0;
}

__global__ void k_hist(const int* __restrict__ ei, int* __restrict__ btot, int E, int NB) {
    __shared__ int hist[512];
    for (int t = threadIdx.x; t < NB; t += 256) hist[t] = 0;
    __syncthreads();
    int base = blockIdx.x * 4096;
#pragma unroll
    for (int k = 0; k < 16; ++k) {
        int e = base + k * 256 + threadIdx.x;
        if (e < E) atomicAdd(&hist[ei[e] >> 8], 1);
    }
    __syncthreads();
    for (int t = threadIdx.x; t < NB; t += 256) {
        int c = hist[t];
        if (c) atomicAdd(&btot[t], c);
    }
}

__global__ void k_scanb(const int* __restrict__ btot, int* __restrict__ bstart,
                        int* __restrict__ bcur, int* __restrict__ row_ptr,
                        int NB, int N, int E) {
    __shared__ int lds[512];
    int t = threadIdx.x;
    int v0 = (t < NB) ? btot[t] : 0;
    int v = v0;
    lds[t] = v;
    __syncthreads();
    for (int o = 1; o < 512; o <<= 1) {
        int a = (t >= o) ? lds[t - o] : 0;
        __syncthreads();
        v += a;
        lds[t] = v;
        __syncthreads();
    }
    if (t < NB) {
        int ex = v - v0;
        bstart[t] = ex;
        bcur[t] = ex;
    }
    if (t == 0) {
        bstart[NB] = E;
        row_ptr[N] = E;
    }
}

// partition edges into bucket slices; entry packed as col | (row&255)<<24 (col < 2^17)
__launch_bounds__(256)
__global__ void k_part(const int* __restrict__ ei, int* __restrict__ bcur,
                       unsigned* __restrict__ ebuf, int E, int NB) {
    __shared__ int hist[512], rebase[512], lcur[512];
    for (int t = threadIdx.x; t < NB; t += 256) { hist[t] = 0; lcur[t] = 0; }
    __syncthreads();
    int base = blockIdx.x * 4096;
    int r[16], c[16];
#pragma unroll
    for (int k = 0; k < 16; ++k) {
        int e = base + k * 256 + threadIdx.x;
        bool ok = e < E;
        r[k] = ok ? ei[e] : -1;
        c[k] = ok ? ei[E + e] : 0;
        if (ok) atomicAdd(&hist[r[k] >> 8], 1);
    }
    __syncthreads();
    for (int t = threadIdx.x; t < NB; t += 256) {
        int cnt = hist[t];
        rebase[t] = cnt ? atomicAdd(&bcur[t], cnt) : 0;
    }
    __syncthreads();
#pragma unroll
    for (int k = 0; k < 16; ++k) {
        if (r[k] >= 0) {
            int b = r[k] >> 8;
            int pos = rebase[b] + atomicAdd(&lcur[b], 1);
            ebuf[pos] = (unsigned)c[k] | ((unsigned)(r[k] & 255) << 24);
        }
    }
}

__launch_bounds__(256)
__global__ void k_bucket(const unsigned* __restrict__ ebuf, const int* __restrict__ bstart,
                         int* __restrict__ row_ptr, float* __restrict__ dinv,
                         int* __restrict__ cols, int N) {
    __shared__ int cnt[256], cur[256], lds[256];
    int b = blockIdx.x, t = threadIdx.x;
    int s = bstart[b], e2 = bstart[b + 1];
    cnt[t] = 0;
    __syncthreads();
    for (int i = s + t; i < e2; i += 256) {
        unsigned p = ebuf[i];
        atomicAdd(&cnt[p >> 24], 1);
    }
    __syncthreads();
    int v0 = cnt[t];
    int v = v0;
    lds[t] = v;
    __syncthreads();
    for (int o = 1; o < 256; o <<= 1) {
        int a = (t >= o) ? lds[t - o] : 0;
        __syncthreads();
        v += a;
        lds[t] = v;
        __syncthreads();
    }
    int excl = v - v0;
    int row = (b << 8) + t;
    if (row < N) {
        row_ptr[row] = s + excl;
        dinv[row] = rsqrtf((float)(v0 + 1));
    }
    cur[t] = s + excl;
    __syncthreads();
    for (int i = s + t; i < e2; i += 256) {
        unsigned p = ebuf[i];
        int pos = atomicAdd(&cur[p >> 24], 1);
        cols[pos] = (int)(p & 0x00FFFFFFu);
    }
}

// ---------------- weight packing into MFMA fragment order (hi/lo split) ----------------
__global__ void k_pack_w1(const float* __restrict__ w1, short* __restrict__ w1fh,
                          short* __restrict__ w1fl) {
    int t = blockIdx.x * 256 + threadIdx.x;  // 65536 total
    int j = t & 7, lane = (t >> 3) & 63, nb = (t >> 9) & 3, kb = t >> 11;
    int k = kb * 32 + ((lane >> 4) << 3) + j;
    int c = nb * 16 + (lane & 15);
    short hi, lo;
    splitbf(w1[k * 64 + c], &hi, &lo);
    w1fh[t] = hi;
    w1fl[t] = lo;
}

__global__ void k_pack_w2(const float* __restrict__ w2, short* __restrict__ w2fh,
                          short* __restrict__ w2fl) {
    int t = blockIdx.x * 256 + threadIdx.x;  // 4096 total
    int j = t & 7, lane = (t >> 3) & 63, nb = (t >> 9) & 3, kb = (t >> 11) & 1;
    int k = kb * 32 + ((lane >> 4) << 3) + j;
    int c = nb * 16 + (lane & 15);
    short hi, lo;
    splitbf(w2[k * 64 + c], &hi, &lo);
    w2fh[t] = hi;
    w2fl[t] = lo;
}

// ---------------- fused 2-layer MLP via split-bf16 MFMA (3-term) ----------------
__launch_bounds__(256)
__global__ void k_mlp(const float* __restrict__ x,
                      const short8* __restrict__ w1fh, const short8* __restrict__ w1fl,
                      const float* __restrict__ b1,
                      const short8* __restrict__ w2fh, const short8* __restrict__ w2fl,
                      const float* __restrict__ b2, const float* __restrict__ dinv,
                      unsigned short* __restrict__ ah, unsigned char* __restrict__ u0,
                      int M, int F) {
    __shared__ __align__(16) short c1sh[4][16][64];
    __shared__ __align__(16) short c1sl[4][16][64];
    int tid = threadIdx.x;
    int w = tid >> 6, lane = tid & 63;
    int hi = lane >> 4, lx = lane & 15;
    int rbase = blockIdx.x * 64 + w * 16;
    int row = rbase + lx;
    size_t rowc = (row < M) ? (size_t)row : (size_t)(M - 1);
    const float* xr = x + rowc * (size_t)F + hi * 8;

    f32x4 acc[4];
#pragma unroll
    for (int nb = 0; nb < 4; ++nb) acc[nb] = (f32x4){0.f, 0.f, 0.f, 0.f};

    int KK = F >> 5;
#pragma unroll 2
    for (int kk = 0; kk < KK; ++kk) {
        float4 a0 = *reinterpret_cast<const float4*>(xr + kk * 32);
        float4 a1 = *reinterpret_cast<const float4*>(xr + kk * 32 + 4);
        float av[8] = {a0.x, a0.y, a0.z, a0.w, a1.x, a1.y, a1.z, a1.w};
        short8 afh, afl;
#pragma unroll
        for (int j = 0; j < 8; ++j) {
            short h8, l8;
            splitbf(av[j], &h8, &l8);
            afh[j] = h8;
            afl[j] = l8;
        }
#pragma unroll
        for (int nb = 0; nb < 4; ++nb) {
            short8 bfh = w1fh[(kk * 4 + nb) * 64 + lane];
            short8 bfl = w1fl[(kk * 4 + nb) * 64 + lane];
            acc[nb] = __builtin_amdgcn_mfma_f32_16x16x32_bf16(afh, bfh, acc[nb], 0, 0, 0);
            acc[nb] = __builtin_amdgcn_mfma_f32_16x16x32_bf16(afl, bfh, acc[nb], 0, 0, 0);
            acc[nb] = __builtin_amdgcn_mfma_f32_16x16x32_bf16(afh, bfl, acc[nb], 0, 0, 0);
        }
    }

    short* myh = &c1sh[w][0][0];
    short* myl = &c1sl[w][0][0];
#pragma unroll
    for (int nb = 0; nb < 4; ++nb) {
        int col = nb * 16 + lx;
        float bb = b1[col];
#pragma unroll
        for (int r = 0; r < 4; ++r) {
            int rr = hi * 4 + r;
            float v = fmaxf(acc[nb][r] + bb, 0.f);
            short h8, l8;
            splitbf(v, &h8, &l8);
            myh[rr * 64 + col] = h8;
            myl[rr * 64 + col] = l8;
        }
    }
    __syncthreads();

    f32x4 acc2[4];
#pragma unroll
    for (int nb = 0; nb < 4; ++nb) acc2[nb] = (f32x4){0.f, 0.f, 0.f, 0.f};
#pragma unroll
    for (int kb = 0; kb < 2; ++kb) {
        short8 a2h = *reinterpret_cast<const short8*>(&myh[lx * 64 + kb * 32 + hi * 8]);
        short8 a2l = *reinterpret_cast<const short8*>(&myl[lx * 64 + kb * 32 + hi * 8]);
#pragma unroll
        for (int nb = 0; nb < 4; ++nb) {
            short8 bfh = w2fh[(kb * 4 + nb) * 64 + lane];
            short8 bfl = w2fl[(kb * 4 + nb) * 64 + lane];
            acc2[nb] = __builtin_amdgcn_mfma_f32_16x16x32_bf16(a2h, bfh, acc2[nb], 0, 0, 0);
            acc2[nb] = __builtin_amdgcn_mfma_f32_16x16x32_bf16(a2l, bfh, acc2[nb], 0, 0, 0);
            acc2[nb] = __builtin_amdgcn_mfma_f32_16x16x32_bf16(a2h, bfl, acc2[nb], 0, 0, 0);
        }
    }

#pragma unroll
    for (int r = 0; r < 4; ++r) {
        int orow = rbase + hi * 4 + r;
        float dv = (orow < M) ? dinv[orow] : 0.f;
#pragma unroll
        for (int nb = 0; nb < 4; ++nb) {
            int col = nb * 16 + lx;
            if (orow < M) {
                float v = acc2[nb][r] + b2[col];
                ah[(size_t)orow * 64 + col] = f2bf(0.1f * v);
                u0[(size_t)orow * 64 + col] = f2fp8(dv * v);
            }
        }
    }
}

// ---------------- propagation (pull over CSR, fp8 u-state, 8-deep ILP) ----------------
__global__ void k_prop(const unsigned char* __restrict__ uin, const unsigned short* __restrict__ ah,
                       const float* __restrict__ dinv, const int* __restrict__ row_ptr,
                       const int* __restrict__ cols, unsigned char* __restrict__ uout, int n) {
    int wid = threadIdx.x >> 6;
    int lane = threadIdx.x & 63;
    int i = blockIdx.x * 4 + wid;
    if (i >= n) return;
    float di = dinv[i];
    size_t i64 = (size_t)i * 64;
    float ui = fp82f(uin[i64 + lane]);
    int e = row_ptr[i], end = row_ptr[i + 1];
    float a0 = 0.f, a1 = 0.f, a2 = 0.f, a3 = 0.f, a4 = 0.f, a5 = 0.f, a6 = 0.f, a7 = 0.f;
    for (; e + 8 <= end; e += 8) {
        int c0 = cols[e],     c1 = cols[e + 1], c2 = cols[e + 2], c3 = cols[e + 3];
        int c4 = cols[e + 4], c5 = cols[e + 5], c6 = cols[e + 6], c7 = cols[e + 7];
        unsigned b0 = uin[(size_t)c0 * 64 + lane];
        unsigned b1 = uin[(size_t)c1 * 64 + lane];
        unsigned b2 = uin[(size_t)c2 * 64 + lane];
        unsigned b3 = uin[(size_t)c3 * 64 + lane];
        unsigned b4 = uin[(size_t)c4 * 64 + lane];
        unsigned b5 = uin[(size_t)c5 * 64 + lane];
        unsigned b6 = uin[(size_t)c6 * 64 + lane];
        unsigned b7 = uin[(size_t)c7 * 64 + lane];
        a0 += fp82f(b0); a1 += fp82f(b1); a2 += fp82f(b2); a3 += fp82f(b3);
        a4 += fp82f(b4); a5 += fp82f(b5); a6 += fp82f(b6); a7 += fp82f(b7);
    }
    for (; e < end; ++e) a0 += fp82f(uin[(size_t)cols[e] * 64 + lane]);
    float s = ((a0 + a1) + (a2 + a3)) + ((a4 + a5) + (a6 + a7)) + ui;
    float z = fmaf(0.9f * di, s, bf2f(ah[i64 + lane]));
    uout[i64 + lane] = f2fp8(di * z);
}

// final step fused with log_softmax, writes f32 out
__global__ void k_prop_lsm(const unsigned char* __restrict__ uin, const unsigned short* __restrict__ ah,
                           const float* __restrict__ dinv, const int* __restrict__ row_ptr,
                           const int* __restrict__ cols, float* __restrict__ out, int n) {
    int wid = threadIdx.x >> 6;
    int lane = threadIdx.x & 63;
    int i = blockIdx.x * 4 + wid;
    if (i >= n) return;
    float di = dinv[i];
    size_t i64 = (size_t)i * 64;
    float ui = fp82f(uin[i64 + lane]);
    int e = row_ptr[i], end = row_ptr[i + 1];
    float a0 = 0.f, a1 = 0.f, a2 = 0.f, a3 = 0.f, a4 = 0.f, a5 = 0.f, a6 = 0.f, a7 = 0.f;
    for (; e + 8 <= end; e += 8) {
        int c0 = cols[e],     c1 = cols[e + 1], c2 = cols[e + 2], c3 = cols[e + 3];
        int c4 = cols[e + 4], c5 = cols[e + 5], c6 = cols[e + 6], c7 = cols[e + 7];
        unsigned b0 = uin[(size_t)c0 * 64 + lane];
        unsigned b1 = uin[(size_t)c1 * 64 + lane];
        unsigned b2 = uin[(size_t)c2 * 64 + lane];
        unsigned b3 = uin[(size_t)c3 * 64 + lane];
        unsigned b4 = uin[(size_t)c4 * 64 + lane];
        unsigned b5 = uin[(size_t)c5 * 64 + lane];
        unsigned b6 = uin[(size_t)c6 * 64 + lane];
        unsigned b7 = uin[(size_t)c7 * 64 + lane];
        a0 += fp82f(b0); a1 += fp82f(b1); a2 += fp82f(b2); a3 += fp82f(b3);
        a4 += fp82f(b4); a5 += fp82f(b5); a6 += fp82f(b6); a7 += fp82f(b7);
    }
    for (; e < end; ++e) a0 += fp82f(uin[(size_t)cols[e] * 64 + lane]);
    float s = ((a0 + a1) + (a2 + a3)) + ((a4 + a5) + (a6 + a7)) + ui;
    float acc = fmaf(0.9f * di, s, bf2f(ah[i64 + lane]));
    float m = acc;
    for (int o = 32; o; o >>= 1) m = fmaxf(m, __shfl_xor(m, o, 64));
    float pp = expf(acc - m);
    float ss = pp;
    for (int o = 32; o; o >>= 1) ss += __shfl_xor(ss, o, 64);
    out[i64 + lane] = (acc - m) - logf(ss);
}

// ---------------- launch ----------------
extern "C" void kernel_launch(void* const* d_in, const int* in_sizes, int n_in,
                              void* d_out, int out_size, void* d_ws, size_t ws_size,
                              hipStream_t stream) {
    const float* x  = (const float*)d_in[0];
    const float* w1 = (const float*)d_in[1];
    const float* b1 = (const float*)d_in[2];
    const float* w2 = (const float*)d_in[3];
    const float* b2 = (const float*)d_in[4];
    const int*   ei = (const int*)d_in[5];
    // d_in[6] = K (always 10; launch count must be graph-static)

    int F = in_sizes[1] / 64;         // 1024
    int N = in_sizes[0] / F;          // 100000
    int E = in_sizes[5] / 2;          // 3200000
    int NB = (N + 255) >> 8;          // 391 buckets

    char* p = (char*)d_ws;
    auto alloc = [&](size_t bytes) {
        void* r = (void*)p;
        p += (bytes + 255) & ~(size_t)255;
        return r;
    };
    unsigned short* ah   = (unsigned short*)alloc((size_t)N * 64 * 2);
    unsigned char*  u0   = (unsigned char*)alloc((size_t)N * 64);
    unsigned char*  uA   = (unsigned char*)alloc((size_t)N * 64);
    unsigned char*  uB   = (unsigned char*)alloc((size_t)N * 64);
    float* dinv    = (float*)alloc((size_t)N * 4);
    int*   row_ptr = (int*)alloc((size_t)(N + 1) * 4);
    int*   btot    = (int*)alloc(2048);
    int*   bstart  = (int*)alloc(2048);
    int*   bcur    = (int*)alloc(2048);
    unsigned* ebuf = (unsigned*)alloc((size_t)E * 4);
    int*   cols    = (int*)alloc((size_t)E * 4);
    short* w1fh    = (short*)alloc((size_t)F * 64 * 2);
    short* w1fl    = (short*)alloc((size_t)F * 64 * 2);
    short* w2fh    = (short*)alloc((size_t)64 * 64 * 2);
    short* w2fl    = (short*)alloc((size_t)64 * 64 * 2);

    int neb = (E + 4095) / 4096;

    k_zero<<<2, 256, 0, stream>>>(btot, NB);
    k_hist<<<neb, 256, 0, stream>>>(ei, btot, E, NB);
    k_scanb<<<1, 512, 0, stream>>>(btot, bstart, bcur, row_ptr, NB, N, E);
    k_part<<<neb, 256, 0, stream>>>(ei, bcur, ebuf, E, NB);
    k_bucket<<<NB, 256, 0, stream>>>(ebuf, bstart, row_ptr, dinv, cols, N);
    k_pack_w1<<<(F * 64) / 256, 256, 0, stream>>>(w1, w1fh, w1fl);
    k_pack_w2<<<16, 256, 0, stream>>>(w2, w2fh, w2fl);
    k_mlp<<<(N + 63) / 64, 256, 0, stream>>>(x, (const short8*)w1fh, (const short8*)w1fl, b1,
                                             (const short8*)w2fh, (const short8*)w2fl, b2,
                                             dinv, ah, u0, N, F);

    const unsigned char* uin = u0;
    unsigned char* bufs[2] = {uA, uB};
    for (int k = 0; k < KSTEPS - 1; ++k) {
        unsigned char* uo = bufs[k & 1];
        k_prop<<<(N + 3) / 4, 256, 0, stream>>>(uin, ah, dinv, row_ptr, cols, uo, N);
        uin = uo;
    }
    k_prop_lsm<<<(N + 3) / 4, 256, 0, stream>>>(uin, ah, dinv, row_ptr, cols, (float*)d_out, N);
}

// Round 8
// 810.442 us; speedup vs baseline: 1.5385x; 1.3563x over previous
//
#include <hip/hip_runtime.h>
#include <math.h>

// APPNP: h = relu(x@W1+b1)@W2+b2 ; z_{k+1} = 0.9*Ahat z_k + 0.1*h (10 steps); log_softmax
// Ahat = D^-1/2 (A + I) D^-1/2.
// u-space propagation: u = D^-1/2 z -> (Ahat z)_i = dinv_i * (sum_{j in N(i)} u_j + u_i).
// CSR via bucketed counting sort. MLP via split-bf16 3-term MFMA. u in fp8 e4m3.
// Prop v3: two adjacent rows per wave (32 lanes each, 2 features/lane) -> 2 edges per
// gather instruction, 8-deep unroll kept (16 edges in flight/wave).

constexpr int KSTEPS = 10;

typedef __attribute__((ext_vector_type(8))) short short8;
typedef __attribute__((ext_vector_type(4))) float f32x4;

static __device__ __forceinline__ unsigned short f2bf(float f) {
    unsigned u = __builtin_bit_cast(unsigned, f);
    unsigned r = (u + 0x7FFFu + ((u >> 16) & 1u)) >> 16;
    return (unsigned short)r;
}
static __device__ __forceinline__ float bf2f(unsigned short b) {
    unsigned u = (unsigned)b << 16;
    return __builtin_bit_cast(float, u);
}
static __device__ __forceinline__ void splitbf(float f, short* hi, short* lo) {
    unsigned u = __builtin_bit_cast(unsigned, f);
    *hi = (short)(u >> 16);
    float rem = f - __builtin_bit_cast(float, u & 0xFFFF0000u);
    *lo = (short)f2bf(rem);
}
static __device__ __forceinline__ unsigned char f2fp8(float f) {
    int p = __builtin_amdgcn_cvt_pk_fp8_f32(f, f, 0, false);
    return (unsigned char)(p & 0xFF);
}
static __device__ __forceinline__ float fp82f(unsigned b) {
    return __builtin_amdgcn_cvt_f32_fp8((int)b, 0);
}

// ---------------- bucketed CSR build ----------------

__global__ void k_zero(int* __restrict__ p, int n) {
    int i = blockIdx.x * 256 + threadIdx.x;
    if (i < n) p[i] = 0;
}

__global__ void k_hist(const int* __restrict__ ei, int* __restrict__ btot, int E, int NB) {
    __shared__ int hist[512];
    for (int t = threadIdx.x; t < NB; t += 256) hist[t] = 0;
    __syncthreads();
    int base = blockIdx.x * 4096;
#pragma unroll
    for (int k = 0; k < 16; ++k) {
        int e = base + k * 256 + threadIdx.x;
        if (e < E) atomicAdd(&hist[ei[e] >> 8], 1);
    }
    __syncthreads();
    for (int t = threadIdx.x; t < NB; t += 256) {
        int c = hist[t];
        if (c) atomicAdd(&btot[t], c);
    }
}

__global__ void k_scanb(const int* __restrict__ btot, int* __restrict__ bstart,
                        int* __restrict__ bcur, int* __restrict__ row_ptr,
                        int NB, int N, int E) {
    __shared__ int lds[512];
    int t = threadIdx.x;
    int v0 = (t < NB) ? btot[t] : 0;
    int v = v0;
    lds[t] = v;
    __syncthreads();
    for (int o = 1; o < 512; o <<= 1) {
        int a = (t >= o) ? lds[t - o] : 0;
        __syncthreads();
        v += a;
        lds[t] = v;
        __syncthreads();
    }
    if (t < NB) {
        int ex = v - v0;
        bstart[t] = ex;
        bcur[t] = ex;
    }
    if (t == 0) {
        bstart[NB] = E;
        row_ptr[N] = E;
    }
}

__launch_bounds__(256)
__global__ void k_part(const int* __restrict__ ei, int* __restrict__ bcur,
                       unsigned* __restrict__ ebuf, int E, int NB) {
    __shared__ int hist[512], rebase[512], lcur[512];
    for (int t = threadIdx.x; t < NB; t += 256) { hist[t] = 0; lcur[t] = 0; }
    __syncthreads();
    int base = blockIdx.x * 4096;
    int r[16], c[16];
#pragma unroll
    for (int k = 0; k < 16; ++k) {
        int e = base + k * 256 + threadIdx.x;
        bool ok = e < E;
        r[k] = ok ? ei[e] : -1;
        c[k] = ok ? ei[E + e] : 0;
        if (ok) atomicAdd(&hist[r[k] >> 8], 1);
    }
    __syncthreads();
    for (int t = threadIdx.x; t < NB; t += 256) {
        int cnt = hist[t];
        rebase[t] = cnt ? atomicAdd(&bcur[t], cnt) : 0;
    }
    __syncthreads();
#pragma unroll
    for (int k = 0; k < 16; ++k) {
        if (r[k] >= 0) {
            int b = r[k] >> 8;
            int pos = rebase[b] + atomicAdd(&lcur[b], 1);
            ebuf[pos] = (unsigned)c[k] | ((unsigned)(r[k] & 255) << 24);
        }
    }
}

__launch_bounds__(256)
__global__ void k_bucket(const unsigned* __restrict__ ebuf, const int* __restrict__ bstart,
                         int* __restrict__ row_ptr, float* __restrict__ dinv,
                         int* __restrict__ cols, int N) {
    __shared__ int cnt[256], cur[256], lds[256];
    int b = blockIdx.x, t = threadIdx.x;
    int s = bstart[b], e2 = bstart[b + 1];
    cnt[t] = 0;
    __syncthreads();
    for (int i = s + t; i < e2; i += 256) {
        unsigned p = ebuf[i];
        atomicAdd(&cnt[p >> 24], 1);
    }
    __syncthreads();
    int v0 = cnt[t];
    int v = v0;
    lds[t] = v;
    __syncthreads();
    for (int o = 1; o < 256; o <<= 1) {
        int a = (t >= o) ? lds[t - o] : 0;
        __syncthreads();
        v += a;
        lds[t] = v;
        __syncthreads();
    }
    int excl = v - v0;
    int row = (b << 8) + t;
    if (row < N) {
        row_ptr[row] = s + excl;
        dinv[row] = rsqrtf((float)(v0 + 1));
    }
    cur[t] = s + excl;
    __syncthreads();
    for (int i = s + t; i < e2; i += 256) {
        unsigned p = ebuf[i];
        int pos = atomicAdd(&cur[p >> 24], 1);
        cols[pos] = (int)(p & 0x00FFFFFFu);
    }
}

// zero-pad row N of the u buffers (predicated tail gathers land here)
__global__ void k_zrow(unsigned char* __restrict__ a, unsigned char* __restrict__ b,
                       unsigned char* __restrict__ c, int N) {
    int t = threadIdx.x;  // 64
    size_t o = (size_t)N * 64 + t;
    a[o] = 0; b[o] = 0; c[o] = 0;
}

// ---------------- weight packing (hi/lo split) ----------------
__global__ void k_pack_w1(const float* __restrict__ w1, short* __restrict__ w1fh,
                          short* __restrict__ w1fl) {
    int t = blockIdx.x * 256 + threadIdx.x;  // 65536 total
    int j = t & 7, lane = (t >> 3) & 63, nb = (t >> 9) & 3, kb = t >> 11;
    int k = kb * 32 + ((lane >> 4) << 3) + j;
    int c = nb * 16 + (lane & 15);
    short hi, lo;
    splitbf(w1[k * 64 + c], &hi, &lo);
    w1fh[t] = hi;
    w1fl[t] = lo;
}

__global__ void k_pack_w2(const float* __restrict__ w2, short* __restrict__ w2fh,
                          short* __restrict__ w2fl) {
    int t = blockIdx.x * 256 + threadIdx.x;  // 4096 total
    int j = t & 7, lane = (t >> 3) & 63, nb = (t >> 9) & 3, kb = (t >> 11) & 1;
    int k = kb * 32 + ((lane >> 4) << 3) + j;
    int c = nb * 16 + (lane & 15);
    short hi, lo;
    splitbf(w2[k * 64 + c], &hi, &lo);
    w2fh[t] = hi;
    w2fl[t] = lo;
}

// ---------------- fused 2-layer MLP via split-bf16 MFMA (3-term) ----------------
__launch_bounds__(256)
__global__ void k_mlp(const float* __restrict__ x,
                      const short8* __restrict__ w1fh, const short8* __restrict__ w1fl,
                      const float* __restrict__ b1,
                      const short8* __restrict__ w2fh, const short8* __restrict__ w2fl,
                      const float* __restrict__ b2, const float* __restrict__ dinv,
                      unsigned short* __restrict__ ah, unsigned char* __restrict__ u0,
                      int M, int F) {
    __shared__ __align__(16) short c1sh[4][16][64];
    __shared__ __align__(16) short c1sl[4][16][64];
    int tid = threadIdx.x;
    int w = tid >> 6, lane = tid & 63;
    int hi = lane >> 4, lx = lane & 15;
    int rbase = blockIdx.x * 64 + w * 16;
    int row = rbase + lx;
    size_t rowc = (row < M) ? (size_t)row : (size_t)(M - 1);
    const float* xr = x + rowc * (size_t)F + hi * 8;

    f32x4 acc[4];
#pragma unroll
    for (int nb = 0; nb < 4; ++nb) acc[nb] = (f32x4){0.f, 0.f, 0.f, 0.f};

    int KK = F >> 5;
#pragma unroll 2
    for (int kk = 0; kk < KK; ++kk) {
        float4 a0 = *reinterpret_cast<const float4*>(xr + kk * 32);
        float4 a1 = *reinterpret_cast<const float4*>(xr + kk * 32 + 4);
        float av[8] = {a0.x, a0.y, a0.z, a0.w, a1.x, a1.y, a1.z, a1.w};
        short8 afh, afl;
#pragma unroll
        for (int j = 0; j < 8; ++j) {
            short h8, l8;
            splitbf(av[j], &h8, &l8);
            afh[j] = h8;
            afl[j] = l8;
        }
#pragma unroll
        for (int nb = 0; nb < 4; ++nb) {
            short8 bfh = w1fh[(kk * 4 + nb) * 64 + lane];
            short8 bfl = w1fl[(kk * 4 + nb) * 64 + lane];
            acc[nb] = __builtin_amdgcn_mfma_f32_16x16x32_bf16(afh, bfh, acc[nb], 0, 0, 0);
            acc[nb] = __builtin_amdgcn_mfma_f32_16x16x32_bf16(afl, bfh, acc[nb], 0, 0, 0);
            acc[nb] = __builtin_amdgcn_mfma_f32_16x16x32_bf16(afh, bfl, acc[nb], 0, 0, 0);
        }
    }

    short* myh = &c1sh[w][0][0];
    short* myl = &c1sl[w][0][0];
#pragma unroll
    for (int nb = 0; nb < 4; ++nb) {
        int col = nb * 16 + lx;
        float bb = b1[col];
#pragma unroll
        for (int r = 0; r < 4; ++r) {
            int rr = hi * 4 + r;
            float v = fmaxf(acc[nb][r] + bb, 0.f);
            short h8, l8;
            splitbf(v, &h8, &l8);
            myh[rr * 64 + col] = h8;
            myl[rr * 64 + col] = l8;
        }
    }
    __syncthreads();

    f32x4 acc2[4];
#pragma unroll
    for (int nb = 0; nb < 4; ++nb) acc2[nb] = (f32x4){0.f, 0.f, 0.f, 0.f};
#pragma unroll
    for (int kb = 0; kb < 2; ++kb) {
        short8 a2h = *reinterpret_cast<const short8*>(&myh[lx * 64 + kb * 32 + hi * 8]);
        short8 a2l = *reinterpret_cast<const short8*>(&myl[lx * 64 + kb * 32 + hi * 8]);
#pragma unroll
        for (int nb = 0; nb < 4; ++nb) {
            short8 bfh = w2fh[(kb * 4 + nb) * 64 + lane];
            short8 bfl = w2fl[(kb * 4 + nb) * 64 + lane];
            acc2[nb] = __builtin_amdgcn_mfma_f32_16x16x32_bf16(a2h, bfh, acc2[nb], 0, 0, 0);
            acc2[nb] = __builtin_amdgcn_mfma_f32_16x16x32_bf16(a2l, bfh, acc2[nb], 0, 0, 0);
            acc2[nb] = __builtin_amdgcn_mfma_f32_16x16x32_bf16(a2h, bfl, acc2[nb], 0, 0, 0);
        }
    }

#pragma unroll
    for (int r = 0; r < 4; ++r) {
        int orow = rbase + hi * 4 + r;
        float dv = (orow < M) ? dinv[orow] : 0.f;
#pragma unroll
        for (int nb = 0; nb < 4; ++nb) {
            int col = nb * 16 + lx;
            if (orow < M) {
                float v = acc2[nb][r] + b2[col];
                ah[(size_t)orow * 64 + col] = f2bf(0.1f * v);
                u0[(size_t)orow * 64 + col] = f2fp8(dv * v);
            }
        }
    }
}

// ---------------- propagation v3: 2 adjacent rows per wave ----------------
// wave w handles rows (2w, 2w+1); half = lane>>5 selects row; fl = lane&31 owns
// features 2fl, 2fl+1. Each gather instruction covers both rows (2x64B). 8-deep unroll.
__global__ void k_prop(const unsigned char* __restrict__ uin, const unsigned short* __restrict__ ah,
                       const float* __restrict__ dinv, const int* __restrict__ row_ptr,
                       const int* __restrict__ cols, unsigned char* __restrict__ uout,
                       int n, int E) {
    int wid = threadIdx.x >> 6;
    int lane = threadIdx.x & 63;
    int half = lane >> 5, fl = lane & 31;
    int r0 = blockIdx.x * 8 + wid * 2;
    int ra = min(r0, n - 1), rb = min(r0 + 1, n - 1);
    int ea = row_ptr[ra], enda = row_ptr[ra + 1];
    int eb = row_ptr[rb], endb = row_ptr[rb + 1];
    int trips = (max(enda - ea, endb - eb) + 7) >> 3;
    int e0 = half ? eb : ea;
    int end_ = half ? endb : enda;
    int r = half ? rb : ra;

    float s0 = 0.f, s1 = 0.f, s2 = 0.f, s3 = 0.f, s4 = 0.f, s5 = 0.f, s6 = 0.f, s7 = 0.f;
    float t0 = 0.f, t1 = 0.f, t2 = 0.f, t3 = 0.f, t4 = 0.f, t5 = 0.f, t6 = 0.f, t7 = 0.f;
    for (int t = 0; t < trips; ++t) {
        int base = e0 + t * 8;
        int ep0 = base,     ep1 = base + 1, ep2 = base + 2, ep3 = base + 3;
        int ep4 = base + 4, ep5 = base + 5, ep6 = base + 6, ep7 = base + 7;
        int c0 = (ep0 < end_) ? cols[min(ep0, E - 1)] : n;
        int c1 = (ep1 < end_) ? cols[min(ep1, E - 1)] : n;
        int c2 = (ep2 < end_) ? cols[min(ep2, E - 1)] : n;
        int c3 = (ep3 < end_) ? cols[min(ep3, E - 1)] : n;
        int c4 = (ep4 < end_) ? cols[min(ep4, E - 1)] : n;
        int c5 = (ep5 < end_) ? cols[min(ep5, E - 1)] : n;
        int c6 = (ep6 < end_) ? cols[min(ep6, E - 1)] : n;
        int c7 = (ep7 < end_) ? cols[min(ep7, E - 1)] : n;
        unsigned v0 = *reinterpret_cast<const unsigned short*>(uin + (size_t)c0 * 64 + fl * 2);
        unsigned v1 = *reinterpret_cast<const unsigned short*>(uin + (size_t)c1 * 64 + fl * 2);
        unsigned v2 = *reinterpret_cast<const unsigned short*>(uin + (size_t)c2 * 64 + fl * 2);
        unsigned v3 = *reinterpret_cast<const unsigned short*>(uin + (size_t)c3 * 64 + fl * 2);
        unsigned v4 = *reinterpret_cast<const unsigned short*>(uin + (size_t)c4 * 64 + fl * 2);
        unsigned v5 = *reinterpret_cast<const unsigned short*>(uin + (size_t)c5 * 64 + fl * 2);
        unsigned v6 = *reinterpret_cast<const unsigned short*>(uin + (size_t)c6 * 64 + fl * 2);
        unsigned v7 = *reinterpret_cast<const unsigned short*>(uin + (size_t)c7 * 64 + fl * 2);
        s0 += fp82f(v0 & 0xFF); t0 += fp82f(v0 >> 8);
        s1 += fp82f(v1 & 0xFF); t1 += fp82f(v1 >> 8);
        s2 += fp82f(v2 & 0xFF); t2 += fp82f(v2 >> 8);
        s3 += fp82f(v3 & 0xFF); t3 += fp82f(v3 >> 8);
        s4 += fp82f(v4 & 0xFF); t4 += fp82f(v4 >> 8);
        s5 += fp82f(v5 & 0xFF); t5 += fp82f(v5 >> 8);
        s6 += fp82f(v6 & 0xFF); t6 += fp82f(v6 >> 8);
        s7 += fp82f(v7 & 0xFF); t7 += fp82f(v7 >> 8);
    }
    float sa = ((s0 + s1) + (s2 + s3)) + ((s4 + s5) + (s6 + s7));
    float sb = ((t0 + t1) + (t2 + t3)) + ((t4 + t5) + (t6 + t7));
    unsigned sv = *reinterpret_cast<const unsigned short*>(uin + (size_t)r * 64 + fl * 2);
    unsigned av = *reinterpret_cast<const unsigned*>(ah + (size_t)r * 64 + fl * 2);
    float di = dinv[r];
    float w = 0.9f * di;
    float z0 = fmaf(w, sa + fp82f(sv & 0xFF), bf2f((unsigned short)(av & 0xFFFF)));
    float z1 = fmaf(w, sb + fp82f(sv >> 8), bf2f((unsigned short)(av >> 16)));
    if (blockIdx.x * 8 + wid * 2 + half < n) {
        unsigned short o = (unsigned short)((unsigned)f2fp8(di * z0) | ((unsigned)f2fp8(di * z1) << 8));
        *reinterpret_cast<unsigned short*>(uout + (size_t)r * 64 + fl * 2) = o;
    }
}

// final step fused with log_softmax, writes f32 out
__global__ void k_prop_lsm(const unsigned char* __restrict__ uin, const unsigned short* __restrict__ ah,
                           const float* __restrict__ dinv, const int* __restrict__ row_ptr,
                           const int* __restrict__ cols, float* __restrict__ out,
                           int n, int E) {
    int wid = threadIdx.x >> 6;
    int lane = threadIdx.x & 63;
    int half = lane >> 5, fl = lane & 31;
    int r0 = blockIdx.x * 8 + wid * 2;
    int ra = min(r0, n - 1), rb = min(r0 + 1, n - 1);
    int ea = row_ptr[ra], enda = row_ptr[ra + 1];
    int eb = row_ptr[rb], endb = row_ptr[rb + 1];
    int trips = (max(enda - ea, endb - eb) + 7) >> 3;
    int e0 = half ? eb : ea;
    int end_ = half ? endb : enda;
    int r = half ? rb : ra;

    float s0 = 0.f, s1 = 0.f, s2 = 0.f, s3 = 0.f, s4 = 0.f, s5 = 0.f, s6 = 0.f, s7 = 0.f;
    float t0 = 0.f, t1 = 0.f, t2 = 0.f, t3 = 0.f, t4 = 0.f, t5 = 0.f, t6 = 0.f, t7 = 0.f;
    for (int t = 0; t < trips; ++t) {
        int base = e0 + t * 8;
        int ep0 = base,     ep1 = base + 1, ep2 = base + 2, ep3 = base + 3;
        int ep4 = base + 4, ep5 = base + 5, ep6 = base + 6, ep7 = base + 7;
        int c0 = (ep0 < end_) ? cols[min(ep0, E - 1)] : n;
        int c1 = (ep1 < end_) ? cols[min(ep1, E - 1)] : n;
        int c2 = (ep2 < end_) ? cols[min(ep2, E - 1)] : n;
        int c3 = (ep3 < end_) ? cols[min(ep3, E - 1)] : n;
        int c4 = (ep4 < end_) ? cols[min(ep4, E - 1)] : n;
        int c5 = (ep5 < end_) ? cols[min(ep5, E - 1)] : n;
        int c6 = (ep6 < end_) ? cols[min(ep6, E - 1)] : n;
        int c7 = (ep7 < end_) ? cols[min(ep7, E - 1)] : n;
        unsigned v0 = *reinterpret_cast<const unsigned short*>(uin + (size_t)c0 * 64 + fl * 2);
        unsigned v1 = *reinterpret_cast<const unsigned short*>(uin + (size_t)c1 * 64 + fl * 2);
        unsigned v2 = *reinterpret_cast<const unsigned short*>(uin + (size_t)c2 * 64 + fl * 2);
        unsigned v3 = *reinterpret_cast<const unsigned short*>(uin + (size_t)c3 * 64 + fl * 2);
        unsigned v4 = *reinterpret_cast<const unsigned short*>(uin + (size_t)c4 * 64 + fl * 2);
        unsigned v5 = *reinterpret_cast<const unsigned short*>(uin + (size_t)c5 * 64 + fl * 2);
        unsigned v6 = *reinterpret_cast<const unsigned short*>(uin + (size_t)c6 * 64 + fl * 2);
        unsigned v7 = *reinterpret_cast<const unsigned short*>(uin + (size_t)c7 * 64 + fl * 2);
        s0 += fp82f(v0 & 0xFF); t0 += fp82f(v0 >> 8);
        s1 += fp82f(v1 & 0xFF); t1 += fp82f(v1 >> 8);
        s2 += fp82f(v2 & 0xFF); t2 += fp82f(v2 >> 8);
        s3 += fp82f(v3 & 0xFF); t3 += fp82f(v3 >> 8);
        s4 += fp82f(v4 & 0xFF); t4 += fp82f(v4 >> 8);
        s5 += fp82f(v5 & 0xFF); t5 += fp82f(v5 >> 8);
        s6 += fp82f(v6 & 0xFF); t6 += fp82f(v6 >> 8);
        s7 += fp82f(v7 & 0xFF); t7 += fp82f(v7 >> 8);
    }
    float sa = ((s0 + s1) + (s2 + s3)) + ((s4 + s5) + (s6 + s7));
    float sb = ((t0 + t1) + (t2 + t3)) + ((t4 + t5) + (t6 + t7));
    unsigned sv = *reinterpret_cast<const unsigned short*>(uin + (size_t)r * 64 + fl * 2);
    unsigned av = *reinterpret_cast<const unsigned*>(ah + (size_t)r * 64 + fl * 2);
    float di = dinv[r];
    float w = 0.9f * di;
    float z0 = fmaf(w, sa + fp82f(sv & 0xFF), bf2f((unsigned short)(av & 0xFFFF)));
    float z1 = fmaf(w, sb + fp82f(sv >> 8), bf2f((unsigned short)(av >> 16)));
    // softmax across the 32 feature-lanes of this half-wave (offsets <32 keep halves apart)
    float m = fmaxf(z0, z1);
#pragma unroll
    for (int o = 1; o <= 16; o <<= 1) m = fmaxf(m, __shfl_xor(m, o, 64));
    float s = expf(z0 - m) + expf(z1 - m);
#pragma unroll
    for (int o = 1; o <= 16; o <<= 1) s += __shfl_xor(s, o, 64);
    float ls = m + logf(s);
    if (blockIdx.x * 8 + wid * 2 + half < n) {
        float2 o2 = make_float2(z0 - ls, z1 - ls);
        *reinterpret_cast<float2*>(out + (size_t)r * 64 + fl * 2) = o2;
    }
}

// ---------------- launch ----------------
extern "C" void kernel_launch(void* const* d_in, const int* in_sizes, int n_in,
                              void* d_out, int out_size, void* d_ws, size_t ws_size,
                              hipStream_t stream) {
    const float* x  = (const float*)d_in[0];
    const float* w1 = (const float*)d_in[1];
    const float* b1 = (const float*)d_in[2];
    const float* w2 = (const float*)d_in[3];
    const float* b2 = (const float*)d_in[4];
    const int*   ei = (const int*)d_in[5];
    // d_in[6] = K (always 10; launch count must be graph-static)

    int F = in_sizes[1] / 64;         // 1024
    int N = in_sizes[0] / F;          // 100000
    int E = in_sizes[5] / 2;          // 3200000
    int NB = (N + 255) >> 8;          // 391 buckets

    char* p = (char*)d_ws;
    auto alloc = [&](size_t bytes) {
        void* r = (void*)p;
        p += (bytes + 255) & ~(size_t)255;
        return r;
    };
    unsigned short* ah   = (unsigned short*)alloc((size_t)N * 64 * 2);
    unsigned char*  u0   = (unsigned char*)alloc((size_t)(N + 1) * 64);
    unsigned char*  uA   = (unsigned char*)alloc((size_t)(N + 1) * 64);
    unsigned char*  uB   = (unsigned char*)alloc((size_t)(N + 1) * 64);
    float* dinv    = (float*)alloc((size_t)N * 4);
    int*   row_ptr = (int*)alloc((size_t)(N + 1) * 4);
    int*   btot    = (int*)alloc(2048);
    int*   bstart  = (int*)alloc(2048);
    int*   bcur    = (int*)alloc(2048);
    unsigned* ebuf = (unsigned*)alloc((size_t)E * 4);
    int*   cols    = (int*)alloc((size_t)E * 4);
    short* w1fh    = (short*)alloc((size_t)F * 64 * 2);
    short* w1fl    = (short*)alloc((size_t)F * 64 * 2);
    short* w2fh    = (short*)alloc((size_t)64 * 64 * 2);
    short* w2fl    = (short*)alloc((size_t)64 * 64 * 2);

    int neb = (E + 4095) / 4096;

    k_zero<<<2, 256, 0, stream>>>(btot, NB);
    k_hist<<<neb, 256, 0, stream>>>(ei, btot, E, NB);
    k_scanb<<<1, 512, 0, stream>>>(btot, bstart, bcur, row_ptr, NB, N, E);
    k_part<<<neb, 256, 0, stream>>>(ei, bcur, ebuf, E, NB);
    k_bucket<<<NB, 256, 0, stream>>>(ebuf, bstart, row_ptr, dinv, cols, N);
    k_zrow<<<1, 64, 0, stream>>>(u0, uA, uB, N);
    k_pack_w1<<<(F * 64) / 256, 256, 0, stream>>>(w1, w1fh, w1fl);
    k_pack_w2<<<16, 256, 0, stream>>>(w2, w2fh, w2fl);
    k_mlp<<<(N + 63) / 64, 256, 0, stream>>>(x, (const short8*)w1fh, (const short8*)w1fl, b1,
                                             (const short8*)w2fh, (const short8*)w2fl, b2,
                                             dinv, ah, u0, N, F);

    const unsigned char* uin = u0;
    unsigned char* bufs[2] = {uA, uB};
    int npb = (N + 7) / 8;  // 8 rows per block (4 waves x 2 rows)
    for (int k = 0; k < KSTEPS - 1; ++k) {
        unsigned char* uo = bufs[k & 1];
        k_prop<<<npb, 256, 0, stream>>>(uin, ah, dinv, row_ptr, cols, uo, N, E);
        uin = uo;
    }
    k_prop_lsm<<<npb, 256, 0, stream>>>(uin, ah, dinv, row_ptr, cols, (float*)d_out, N, E);
}